// Round 1
// baseline (2439.878 us; speedup 1.0000x reference)
//
#include <hip/hip_runtime.h>

// TalkingHeadAttention: B=4, N=1024, C=768, H=12, HD=64
// Round 1: full fp32 correctness baseline.
//   K1: qkv = inputs @ w_qkv                       (4096x2304, K=768)
//   K2: fused two-pass talking-heads attention -> x (4096x768)
//   K3: out = x @ w_proj + b_proj                  (4096x768, K=768)
// Workspace: qkv (9.44M floats) + x (3.15M floats) = 50.3 MB.

#define Bsz   4
#define Nseq  1024
#define Cdim  768
#define Hn    12
#define HDim  64
#define SCALEQ 0.125f   // 64^-0.5

// ---------------- fp32 tiled GEMM: C[M,N] = A[M,K] @ B[K,N] (+bias) --------
// 128x128 tile, BK=16, 256 threads, 8x8 per thread (4+4 split).
__global__ __launch_bounds__(256) void gemm_f32(
    const float* __restrict__ A, const float* __restrict__ B,
    const float* __restrict__ bias, float* __restrict__ C,
    int M, int N, int K)
{
  __shared__ float As[16][132];   // [k][m], padded
  __shared__ float Bs[16][132];   // [k][n], padded
  const int tid = threadIdx.x;
  const int tx = tid & 15, ty = tid >> 4;
  const int colC = blockIdx.x * 128;
  const int rowC = blockIdx.y * 128;

  float acc[8][8];
#pragma unroll
  for (int i = 0; i < 8; ++i)
#pragma unroll
    for (int j = 0; j < 8; ++j) acc[i][j] = 0.f;

  const int ar = tid & 127, akh = tid >> 7;        // A-staging role
  const int br = tid >> 4, bc4 = (tid & 15) * 4;   // B-staging role

  for (int kt = 0; kt < K; kt += 16) {
    __syncthreads();
    {
      const float* src = A + (size_t)(rowC + ar) * K + kt + akh * 8;
      float4 a0 = *(const float4*)src;
      float4 a1 = *(const float4*)(src + 4);
      As[akh*8+0][ar] = a0.x; As[akh*8+1][ar] = a0.y;
      As[akh*8+2][ar] = a0.z; As[akh*8+3][ar] = a0.w;
      As[akh*8+4][ar] = a1.x; As[akh*8+5][ar] = a1.y;
      As[akh*8+6][ar] = a1.z; As[akh*8+7][ar] = a1.w;
    }
    {
      const float* src = B + (size_t)(kt + br) * N + colC + bc4;
      *(float4*)&Bs[br][bc4]      = *(const float4*)src;
      *(float4*)&Bs[br][bc4 + 64] = *(const float4*)(src + 64);
    }
    __syncthreads();
#pragma unroll
    for (int k = 0; k < 16; ++k) {
      float4 a0 = *(const float4*)&As[k][ty*4];
      float4 a1 = *(const float4*)&As[k][64 + ty*4];
      float4 b0 = *(const float4*)&Bs[k][tx*4];
      float4 b1 = *(const float4*)&Bs[k][64 + tx*4];
      float av[8] = {a0.x,a0.y,a0.z,a0.w,a1.x,a1.y,a1.z,a1.w};
      float bv[8] = {b0.x,b0.y,b0.z,b0.w,b1.x,b1.y,b1.z,b1.w};
#pragma unroll
      for (int i = 0; i < 8; ++i)
#pragma unroll
        for (int j = 0; j < 8; ++j)
          acc[i][j] = fmaf(av[i], bv[j], acc[i][j]);
    }
  }

#pragma unroll
  for (int ih = 0; ih < 2; ++ih)
#pragma unroll
    for (int i = 0; i < 4; ++i) {
      const int row = rowC + ih*64 + ty*4 + i;
#pragma unroll
      for (int jh = 0; jh < 2; ++jh) {
        const int col = colC + jh*64 + tx*4;
        float4 r;
        r.x = acc[ih*4+i][jh*4+0];
        r.y = acc[ih*4+i][jh*4+1];
        r.z = acc[ih*4+i][jh*4+2];
        r.w = acc[ih*4+i][jh*4+3];
        if (bias) {
          r.x += bias[col+0]; r.y += bias[col+1];
          r.z += bias[col+2]; r.w += bias[col+3];
        }
        *(float4*)&C[(size_t)row * N + col] = r;
      }
    }
}

// ------------- fused talking-heads attention (two-pass, fp32) --------------
// Block = (batch b, 8 q-rows). 256 threads.
// qkv layout: row (b*N+n), col {0:Q,1:K,2:V}*768 + h*64 + d.
// Pass A: running (m,d) per (q, head) via online softmax over k-tiles of 32.
// Pass B: recompute logits, normalize, post-mix w_w (+b_w), PV-accumulate.
__global__ __launch_bounds__(256) void attn_fused(
    const float* __restrict__ qkv,
    const float* __restrict__ w_l, const float* __restrict__ b_l,
    const float* __restrict__ w_w, const float* __restrict__ b_w,
    float* __restrict__ xout)
{
  __shared__ float Qs[8][768];          // q-tile, all heads, pre-scaled
  __shared__ float Kh[32][68];          // per-head K tile
  __shared__ float Vh[32][68];          // per-head V tile
  __shared__ float att2s[8][32][12];    // post-mix probs for current k-tile
  __shared__ float mrun[8][12], dsum[8][12], dinv[8][12];
  __shared__ float wl[144], ww[144], blv[12], bwv[12];

  const int tid = threadIdx.x;
  const int b  = blockIdx.x >> 7;            // 128 q-tiles per batch
  const int q0 = (blockIdx.x & 127) * 8;

  if (tid < 144) { wl[tid] = w_l[tid]; ww[tid] = w_w[tid]; }
  if (tid < 12)  { blv[tid] = b_l[tid]; bwv[tid] = b_w[tid]; }
  if (tid < 96)  { mrun[tid/12][tid%12] = -1e30f; dsum[tid/12][tid%12] = 0.f; }
  {
    const int qq = tid >> 5, l32 = tid & 31;
    const float* src = qkv + (size_t)(b*Nseq + q0 + qq) * (3*Cdim);
#pragma unroll
    for (int j = 0; j < 6; ++j) {
      const int c = l32*4 + j*128;
      float4 v = *(const float4*)(src + c);
      Qs[qq][c+0] = v.x * SCALEQ;
      Qs[qq][c+1] = v.y * SCALEQ;
      Qs[qq][c+2] = v.z * SCALEQ;
      Qs[qq][c+3] = v.w * SCALEQ;
    }
  }
  __syncthreads();

  const int q  = tid >> 5;          // 0..7
  const int kl = tid & 31;          // 0..31
  const int srow = tid >> 3, sd0 = (tid & 7) * 4;   // K/V staging role

  // ---------------- pass A: softmax stats ----------------
  for (int kt = 0; kt < Nseq; kt += 32) {
    float l[12];
#pragma unroll
    for (int g = 0; g < 12; ++g) l[g] = blv[g];
    for (int h = 0; h < 12; ++h) {
      __syncthreads();
      {
        const float* src = qkv + (size_t)(b*Nseq + kt + srow) * (3*Cdim) + Cdim + h*HDim;
        *(float4*)&Kh[srow][sd0]      = *(const float4*)(src + sd0);
        *(float4*)&Kh[srow][sd0 + 32] = *(const float4*)(src + sd0 + 32);
      }
      __syncthreads();
      float s = 0.f;
#pragma unroll
      for (int d4 = 0; d4 < 16; ++d4) {
        float4 qv = *(const float4*)&Qs[q][h*HDim + d4*4];
        float4 kv = *(const float4*)&Kh[kl][d4*4];
        s = fmaf(qv.x, kv.x, s); s = fmaf(qv.y, kv.y, s);
        s = fmaf(qv.z, kv.z, s); s = fmaf(qv.w, kv.w, s);
      }
#pragma unroll
      for (int g = 0; g < 12; ++g) l[g] = fmaf(s, wl[h*12+g], l[g]);
    }
#pragma unroll
    for (int g = 0; g < 12; ++g) {
      float mt = l[g];
#pragma unroll
      for (int mk = 16; mk >= 1; mk >>= 1) mt = fmaxf(mt, __shfl_xor(mt, mk, 64));
      float e = __expf(l[g] - mt);
      float st = e;
#pragma unroll
      for (int mk = 16; mk >= 1; mk >>= 1) st += __shfl_xor(st, mk, 64);
      if (kl == 0) {
        const float mo = mrun[q][g];
        const float mn = fmaxf(mo, mt);
        dsum[q][g] = dsum[q][g] * __expf(mo - mn) + st * __expf(mt - mn);
        mrun[q][g] = mn;
      }
    }
  }
  __syncthreads();
  if (tid < 96) dinv[tid/12][tid%12] = 1.f / dsum[tid/12][tid%12];
  __syncthreads();

  // ---------------- pass B: normalize, mix, PV ----------------
  const int d4  = tid & 15;          // d-chunk (float4)
  const int khf = (tid >> 4) & 1;    // k half (partial sums, combined at end)
  float xacc[12][4];
#pragma unroll
  for (int g = 0; g < 12; ++g)
#pragma unroll
    for (int j = 0; j < 4; ++j) xacc[g][j] = 0.f;

  for (int kt = 0; kt < Nseq; kt += 32) {
    float l[12];
#pragma unroll
    for (int g = 0; g < 12; ++g) l[g] = blv[g];
    for (int h = 0; h < 12; ++h) {
      __syncthreads();
      {
        const float* src = qkv + (size_t)(b*Nseq + kt + srow) * (3*Cdim) + Cdim + h*HDim;
        *(float4*)&Kh[srow][sd0]      = *(const float4*)(src + sd0);
        *(float4*)&Kh[srow][sd0 + 32] = *(const float4*)(src + sd0 + 32);
      }
      __syncthreads();
      float s = 0.f;
#pragma unroll
      for (int d4i = 0; d4i < 16; ++d4i) {
        float4 qv = *(const float4*)&Qs[q][h*HDim + d4i*4];
        float4 kv = *(const float4*)&Kh[kl][d4i*4];
        s = fmaf(qv.x, kv.x, s); s = fmaf(qv.y, kv.y, s);
        s = fmaf(qv.z, kv.z, s); s = fmaf(qv.w, kv.w, s);
      }
#pragma unroll
      for (int g = 0; g < 12; ++g) l[g] = fmaf(s, wl[h*12+g], l[g]);
    }
    float att2[12];
#pragma unroll
    for (int g2 = 0; g2 < 12; ++g2) att2[g2] = bwv[g2];
#pragma unroll
    for (int g = 0; g < 12; ++g) {
      const float p = __expf(l[g] - mrun[q][g]) * dinv[q][g];
#pragma unroll
      for (int g2 = 0; g2 < 12; ++g2) att2[g2] = fmaf(p, ww[g*12+g2], att2[g2]);
    }
#pragma unroll
    for (int g2 = 0; g2 < 12; ++g2) att2s[q][kl][g2] = att2[g2];

    for (int g2 = 0; g2 < 12; ++g2) {
      __syncthreads();   // att2s ready (g2==0) / prev Vh reads done
      {
        const float* src = qkv + (size_t)(b*Nseq + kt + srow) * (3*Cdim) + 2*Cdim + g2*HDim;
        *(float4*)&Vh[srow][sd0]      = *(const float4*)(src + sd0);
        *(float4*)&Vh[srow][sd0 + 32] = *(const float4*)(src + sd0 + 32);
      }
      __syncthreads();
      float4 a = {xacc[g2][0], xacc[g2][1], xacc[g2][2], xacc[g2][3]};
#pragma unroll
      for (int kk2 = 0; kk2 < 16; ++kk2) {
        const int kk = khf*16 + kk2;
        const float p = att2s[q][kk][g2];
        float4 v = *(const float4*)&Vh[kk][d4*4];
        a.x = fmaf(p, v.x, a.x); a.y = fmaf(p, v.y, a.y);
        a.z = fmaf(p, v.z, a.z); a.w = fmaf(p, v.w, a.w);
      }
      xacc[g2][0] = a.x; xacc[g2][1] = a.y;
      xacc[g2][2] = a.z; xacc[g2][3] = a.w;
    }
  }

  // combine k-halves (lane ^ 16 flips khf, keeps q and d4) and write x
#pragma unroll
  for (int g2 = 0; g2 < 12; ++g2) {
    float4 a = {xacc[g2][0], xacc[g2][1], xacc[g2][2], xacc[g2][3]};
    a.x += __shfl_xor(a.x, 16, 64);
    a.y += __shfl_xor(a.y, 16, 64);
    a.z += __shfl_xor(a.z, 16, 64);
    a.w += __shfl_xor(a.w, 16, 64);
    if (khf == 0)
      *(float4*)&xout[(size_t)(b*Nseq + q0 + q) * Cdim + g2*HDim + d4*4] = a;
  }
}

extern "C" void kernel_launch(void* const* d_in, const int* in_sizes, int n_in,
                              void* d_out, int out_size, void* d_ws, size_t ws_size,
                              hipStream_t stream) {
  const float* inputs = (const float*)d_in[0];
  const float* w_qkv  = (const float*)d_in[1];
  const float* w_l    = (const float*)d_in[2];
  const float* b_l    = (const float*)d_in[3];
  const float* w_w    = (const float*)d_in[4];
  const float* b_w    = (const float*)d_in[5];
  const float* w_proj = (const float*)d_in[6];
  const float* b_proj = (const float*)d_in[7];
  float* out = (float*)d_out;

  float* qkv = (float*)d_ws;                         // 4096*2304 floats
  float* x   = qkv + (size_t)Bsz*Nseq*3*Cdim;        // 4096*768 floats

  const int M = Bsz * Nseq;  // 4096
  dim3 blk(256);

  gemm_f32<<<dim3((3*Cdim)/128, M/128), blk, 0, stream>>>(
      inputs, w_qkv, nullptr, qkv, M, 3*Cdim, Cdim);

  attn_fused<<<dim3(Bsz * (Nseq/8)), blk, 0, stream>>>(
      qkv, w_l, b_l, w_w, b_w, x);

  gemm_f32<<<dim3(Cdim/128, M/128), blk, 0, stream>>>(
      x, w_proj, b_proj, out, M, Cdim, Cdim);
}